// Round 4
// baseline (332.052 us; speedup 1.0000x reference)
//
#include <hip/hip_runtime.h>

#define NNODES 50000
#define NEDGES 640000
#define D 128

typedef unsigned short u16;
typedef unsigned int u32;
typedef __bf16 bf16x8 __attribute__((ext_vector_type(8)));
typedef float f32x4 __attribute__((ext_vector_type(4)));
union AB { uint4 u4; bf16x8 f; };

__device__ __forceinline__ u16 f2b(float f) {
    u32 u = __float_as_uint(f);
    return (u16)((u + 0x7fffu + ((u >> 16) & 1u)) >> 16);
}
__device__ __forceinline__ u32 pack2(float lo, float hi) {
    return (u32)f2b(lo) | ((u32)f2b(hi) << 16);
}
__device__ __forceinline__ float blo(u32 v) { return __uint_as_float(v << 16); }
__device__ __forceinline__ float bhi(u32 v) { return __uint_as_float(v & 0xffff0000u); }

__device__ __forceinline__ void acc8(float* a, uint4 v) {
    a[0] += blo(v.x); a[1] += bhi(v.x);
    a[2] += blo(v.y); a[3] += bhi(v.y);
    a[4] += blo(v.z); a[5] += bhi(v.z);
    a[6] += blo(v.w); a[7] += bhi(v.w);
}

// ---------------- CSR build ----------------

__global__ void k_hist(const int* __restrict__ dst, int* __restrict__ cnt) {
    int e = blockIdx.x * 256 + threadIdx.x;
    if (e < NEDGES) atomicAdd(&cnt[dst[e]], 1);
}

__global__ void k_scan1(const int* __restrict__ cnt, int* __restrict__ rp,
                        int* __restrict__ bsum) {
    __shared__ int s[256];
    int tid = threadIdx.x;
    int i = blockIdx.x * 256 + tid;
    int v = (i < NNODES) ? cnt[i] : 0;
    s[tid] = v;
    __syncthreads();
    for (int off = 1; off < 256; off <<= 1) {
        int t = (tid >= off) ? s[tid - off] : 0;
        __syncthreads();
        s[tid] += t;
        __syncthreads();
    }
    if (i < NNODES) rp[i] = s[tid] - v;
    if (tid == 255) bsum[blockIdx.x] = s[255];
}

__global__ void k_scan2(int* __restrict__ bsum, int nb) {
    __shared__ int s[256];
    int tid = threadIdx.x;
    int v = (tid < nb) ? bsum[tid] : 0;
    s[tid] = v;
    __syncthreads();
    for (int off = 1; off < 256; off <<= 1) {
        int t = (tid >= off) ? s[tid - off] : 0;
        __syncthreads();
        s[tid] += t;
        __syncthreads();
    }
    if (tid < nb) bsum[tid] = s[tid] - v;
}

__global__ void k_add(int* __restrict__ rp, const int* __restrict__ bsum) {
    int i = blockIdx.x * 256 + threadIdx.x;
    if (i < NNODES) rp[i] += bsum[blockIdx.x];
    if (i == 0) rp[NNODES] = NEDGES;
}

// reverse-fill using cnt itself (cnt is consumed; no separate fill array)
__global__ void k_scatter(const int* __restrict__ src, const int* __restrict__ dst,
                          const int* __restrict__ rp, int* __restrict__ cnt,
                          int* __restrict__ srcs) {
    int e = blockIdx.x * 256 + threadIdx.x;
    if (e < NEDGES) {
        int dn = dst[e];
        int old = atomicSub(&cnt[dn], 1);
        srcs[rp[dn] + old - 1] = src[e];
    }
}

// ---------------- weight prep (transpose->bf16) + x conversion, merged ----------------
__global__ void k_prep(const float* __restrict__ W1, const float* __restrict__ W2,
                       const float* __restrict__ fw, const float* __restrict__ x,
                       u16* __restrict__ wT1, u16* __restrict__ wT2,
                       u16* __restrict__ fwTc, u32* __restrict__ xb) {
    int idx = blockIdx.x * 256 + threadIdx.x;  // grid covers NNODES*64
    if (idx < 3 * 16384) {
        int l = idx >> 14, r = idx & 16383, n = r >> 7, k = r & 127;
        wT1[idx] = f2b(W1[l * 16384 + k * 128 + n]);
        wT2[idx] = f2b(W2[l * 16384 + k * 128 + n]);
    }
    if (idx < 4 * 16384) {
        int ch = idx >> 14, r = idx & 16383, n = r >> 7, k = r & 127;
        fwTc[idx] = f2b(fw[(ch * 128 + k) * 128 + n]);
    }
    if (idx < NNODES * 64) {
        float2 v = ((const float2*)x)[idx];
        xb[idx] = pack2(v.x, v.y);
    }
}

// ---------------- fused agg + 2-layer MLP ----------------
// Block = 128 nodes. Phase A: gather z=(1+eps)h+sum into fp32 regs (16 lanes/node,
// 8-deep load unroll), write bf16 rows into Tb (chunk-XOR swizzled).
// Phase B: GEMM1 (A from Tb, W1 from wbuf) -> relu -> Tb; GEMM2 -> relu -> Tb -> H.
// LDS swizzle: 16B chunk ch of row r lives at slot (ch+r)&15 -> 2-way banks (free).
__launch_bounds__(256, 2)
__global__ void k_mlp(const uint4* __restrict__ h4, const int* __restrict__ rp,
                      const int* __restrict__ srcs, const float* __restrict__ epsp,
                      const u16* __restrict__ wT1g, const float* __restrict__ b1,
                      const u16* __restrict__ wT2g, const float* __restrict__ b2,
                      u16* __restrict__ H) {
    __shared__ u16 Tb[128 * 128];    // 32 KB
    __shared__ u16 wbuf[128 * 128];  // 32 KB
    uint4* Tb4 = (uint4*)Tb;
    uint4* wb4 = (uint4*)wbuf;
    int tid = threadIdx.x;
    int r0 = blockIdx.x * 128;

    // stage W1^T (swizzled)
    {
        const uint4* g = (const uint4*)wT1g;
        for (int i = tid; i < 2048; i += 256) {
            int n = i >> 4, ch = i & 15;
            wb4[n * 16 + ((ch + n) & 15)] = g[i];
        }
    }

    // ---- Phase A: gather ----
    {
        int c = tid & 15;          // 16B chunk of the 256B row
        int g16 = tid >> 4;        // group 0..15
        int gbase = tid & 48;      // group base lane within wave
        float sc = 1.0f + epsp[0];
        for (int jn = 0; jn < 8; ++jn) {
            int nl = g16 * 8 + jn;         // node_local
            int node = r0 + nl;
            float acc[8] = {0.f, 0.f, 0.f, 0.f, 0.f, 0.f, 0.f, 0.f};
            if (node < NNODES) {
                uint4 sv = h4[node * 16 + c];
                acc[0] = sc * blo(sv.x); acc[1] = sc * bhi(sv.x);
                acc[2] = sc * blo(sv.y); acc[3] = sc * bhi(sv.y);
                acc[4] = sc * blo(sv.z); acc[5] = sc * bhi(sv.z);
                acc[6] = sc * blo(sv.w); acc[7] = sc * bhi(sv.w);
                int beg = rp[node], end = rp[node + 1];
                for (int base = beg; base < end; base += 16) {
                    int n = end - base; if (n > 16) n = 16;
                    int myidx = (base + c < end) ? srcs[base + c] : 0;
                    int j = 0;
                    for (; j + 8 <= n; j += 8) {
                        int s0 = __shfl(myidx, gbase + j + 0, 64);
                        int s1 = __shfl(myidx, gbase + j + 1, 64);
                        int s2 = __shfl(myidx, gbase + j + 2, 64);
                        int s3 = __shfl(myidx, gbase + j + 3, 64);
                        int s4 = __shfl(myidx, gbase + j + 4, 64);
                        int s5 = __shfl(myidx, gbase + j + 5, 64);
                        int s6 = __shfl(myidx, gbase + j + 6, 64);
                        int s7 = __shfl(myidx, gbase + j + 7, 64);
                        uint4 v0 = h4[s0 * 16 + c]; uint4 v1 = h4[s1 * 16 + c];
                        uint4 v2 = h4[s2 * 16 + c]; uint4 v3 = h4[s3 * 16 + c];
                        uint4 v4 = h4[s4 * 16 + c]; uint4 v5 = h4[s5 * 16 + c];
                        uint4 v6 = h4[s6 * 16 + c]; uint4 v7 = h4[s7 * 16 + c];
                        acc8(acc, v0); acc8(acc, v1); acc8(acc, v2); acc8(acc, v3);
                        acc8(acc, v4); acc8(acc, v5); acc8(acc, v6); acc8(acc, v7);
                    }
                    for (; j + 4 <= n; j += 4) {
                        int s0 = __shfl(myidx, gbase + j + 0, 64);
                        int s1 = __shfl(myidx, gbase + j + 1, 64);
                        int s2 = __shfl(myidx, gbase + j + 2, 64);
                        int s3 = __shfl(myidx, gbase + j + 3, 64);
                        uint4 v0 = h4[s0 * 16 + c]; uint4 v1 = h4[s1 * 16 + c];
                        uint4 v2 = h4[s2 * 16 + c]; uint4 v3 = h4[s3 * 16 + c];
                        acc8(acc, v0); acc8(acc, v1); acc8(acc, v2); acc8(acc, v3);
                    }
                    for (; j < n; ++j) {
                        int s0 = __shfl(myidx, gbase + j, 64);
                        uint4 v0 = h4[s0 * 16 + c];
                        acc8(acc, v0);
                    }
                }
            }
            uint4 o;
            o.x = pack2(acc[0], acc[1]); o.y = pack2(acc[2], acc[3]);
            o.z = pack2(acc[4], acc[5]); o.w = pack2(acc[6], acc[7]);
            Tb4[nl * 16 + ((c + nl) & 15)] = o;
        }
    }
    __syncthreads();

    // ---- Phase B ----
    int wave = tid >> 6, lane = tid & 63, l16 = lane & 15, quad = lane >> 4;

    AB a[2][4];
#pragma unroll
    for (int s = 0; s < 2; ++s) {
        int m = wave * 32 + s * 16 + l16;
#pragma unroll
        for (int kb = 0; kb < 4; ++kb)
            a[s][kb].u4 = Tb4[m * 16 + ((kb * 4 + quad + m) & 15)];
    }

    f32x4 acc[2][8];
#pragma unroll
    for (int col = 0; col < 8; ++col) {
        float bv = b1[col * 16 + l16];
        acc[0][col] = (f32x4){bv, bv, bv, bv};
        acc[1][col] = (f32x4){bv, bv, bv, bv};
    }
#pragma unroll
    for (int col = 0; col < 8; ++col) {
#pragma unroll
        for (int kb = 0; kb < 4; ++kb) {
            AB b;
            int n = col * 16 + l16;
            b.u4 = wb4[n * 16 + ((kb * 4 + quad + n) & 15)];
            acc[0][col] = __builtin_amdgcn_mfma_f32_16x16x32_bf16(a[0][kb].f, b.f, acc[0][col], 0, 0, 0);
            acc[1][col] = __builtin_amdgcn_mfma_f32_16x16x32_bf16(a[1][kb].f, b.f, acc[1][col], 0, 0, 0);
        }
    }
    __syncthreads();  // all a-frag reads of Tb done before overwrite

    // T = relu -> Tb (swizzled scalar u16 stores)
#pragma unroll
    for (int s = 0; s < 2; ++s)
#pragma unroll
        for (int col = 0; col < 8; ++col)
#pragma unroll
            for (int r = 0; r < 4; ++r) {
                int row = wave * 32 + s * 16 + quad * 4 + r;
                int kcol = col * 16 + l16;
                int ch = kcol >> 3;
                Tb[row * 128 + ((ch + row) & 15) * 8 + (kcol & 7)] =
                    f2b(fmaxf(acc[s][col][r], 0.f));
            }
    __syncthreads();

    // stage W2^T (swizzled)
    {
        const uint4* g = (const uint4*)wT2g;
        for (int i = tid; i < 2048; i += 256) {
            int n = i >> 4, ch = i & 15;
            wb4[n * 16 + ((ch + n) & 15)] = g[i];
        }
    }
    AB a2[2][4];
#pragma unroll
    for (int s = 0; s < 2; ++s) {
        int m = wave * 32 + s * 16 + l16;
#pragma unroll
        for (int kb = 0; kb < 4; ++kb)
            a2[s][kb].u4 = Tb4[m * 16 + ((kb * 4 + quad + m) & 15)];
    }
    __syncthreads();

#pragma unroll
    for (int col = 0; col < 8; ++col) {
        float bv = b2[col * 16 + l16];
        acc[0][col] = (f32x4){bv, bv, bv, bv};
        acc[1][col] = (f32x4){bv, bv, bv, bv};
    }
#pragma unroll
    for (int col = 0; col < 8; ++col) {
#pragma unroll
        for (int kb = 0; kb < 4; ++kb) {
            AB b;
            int n = col * 16 + l16;
            b.u4 = wb4[n * 16 + ((kb * 4 + quad + n) & 15)];
            acc[0][col] = __builtin_amdgcn_mfma_f32_16x16x32_bf16(a2[0][kb].f, b.f, acc[0][col], 0, 0, 0);
            acc[1][col] = __builtin_amdgcn_mfma_f32_16x16x32_bf16(a2[1][kb].f, b.f, acc[1][col], 0, 0, 0);
        }
    }
    __syncthreads();  // a2 reads of Tb done before overwrite

#pragma unroll
    for (int s = 0; s < 2; ++s)
#pragma unroll
        for (int col = 0; col < 8; ++col)
#pragma unroll
            for (int r = 0; r < 4; ++r) {
                int row = wave * 32 + s * 16 + quad * 4 + r;
                int kcol = col * 16 + l16;
                int ch = kcol >> 3;
                Tb[row * 128 + ((ch + row) & 15) * 8 + (kcol & 7)] =
                    f2b(fmaxf(acc[s][col][r], 0.f));
            }
    __syncthreads();

    // coalesced copy Tb -> H (de-swizzle)
    for (int i = tid; i < 2048; i += 256) {
        int r = i >> 4, ch = i & 15;
        int grow = r0 + r;
        if (grow < NNODES)
            *(uint4*)&H[grow * 128 + ch * 8] = Tb4[r * 16 + ((ch + r) & 15)];
    }
}

// ---------------- final: out = concat(x,h1,h2,h3) @ fw + fb, fp32 out ----------------
__launch_bounds__(256, 2)
__global__ void k_final(const u16* __restrict__ xb, const u16* __restrict__ h1,
                        const u16* __restrict__ h2b, const u16* __restrict__ h3,
                        const u16* __restrict__ fwTc, const float* __restrict__ fb,
                        float* __restrict__ out) {
    __shared__ u16 wbuf[128 * 128];
    uint4* wb4 = (uint4*)wbuf;
    int tid = threadIdx.x;
    int wave = tid >> 6, lane = tid & 63, l16 = lane & 15, quad = lane >> 4;
    int r0 = blockIdx.x * 128 + wave * 32;

    f32x4 acc[2][8];
#pragma unroll
    for (int col = 0; col < 8; ++col) {
        float bv = fb[col * 16 + l16];
        acc[0][col] = (f32x4){bv, bv, bv, bv};
        acc[1][col] = (f32x4){bv, bv, bv, bv};
    }

    const u16* chin[4] = {xb, h1, h2b, h3};
    for (int chn = 0; chn < 4; ++chn) {
        __syncthreads();
        {
            const uint4* g = (const uint4*)(fwTc + chn * 16384);
            for (int i = tid; i < 2048; i += 256) {
                int n = i >> 4, ch = i & 15;
                wb4[n * 16 + ((ch + n) & 15)] = g[i];
            }
        }
        const u16* cp = chin[chn];
        AB a[2][4];
#pragma unroll
        for (int s = 0; s < 2; ++s) {
            int row = r0 + s * 16 + l16;
#pragma unroll
            for (int kb = 0; kb < 4; ++kb) {
                if (row < NNODES)
                    a[s][kb].u4 = *(const uint4*)&cp[row * 128 + kb * 32 + quad * 8];
                else
                    a[s][kb].u4 = make_uint4(0, 0, 0, 0);
            }
        }
        __syncthreads();
#pragma unroll
        for (int col = 0; col < 8; ++col) {
#pragma unroll
            for (int kb = 0; kb < 4; ++kb) {
                AB b;
                int n = col * 16 + l16;
                b.u4 = wb4[n * 16 + ((kb * 4 + quad + n) & 15)];
                acc[0][col] = __builtin_amdgcn_mfma_f32_16x16x32_bf16(a[0][kb].f, b.f, acc[0][col], 0, 0, 0);
                acc[1][col] = __builtin_amdgcn_mfma_f32_16x16x32_bf16(a[1][kb].f, b.f, acc[1][col], 0, 0, 0);
            }
        }
    }

#pragma unroll
    for (int s = 0; s < 2; ++s)
#pragma unroll
        for (int col = 0; col < 8; ++col)
#pragma unroll
            for (int r = 0; r < 4; ++r) {
                int row = r0 + s * 16 + quad * 4 + r;
                if (row < NNODES) out[row * 128 + col * 16 + l16] = acc[s][col][r];
            }
}

extern "C" void kernel_launch(void* const* d_in, const int* in_sizes, int n_in,
                              void* d_out, int out_size, void* d_ws, size_t ws_size,
                              hipStream_t stream) {
    const float* x   = (const float*)d_in[0];
    const int*   ei  = (const int*)d_in[1];
    const float* W1  = (const float*)d_in[2];
    const float* b1  = (const float*)d_in[3];
    const float* W2  = (const float*)d_in[4];
    const float* b2  = (const float*)d_in[5];
    const float* eps = (const float*)d_in[6];
    const float* fw  = (const float*)d_in[7];
    const float* fb  = (const float*)d_in[8];
    float* out = (float*)d_out;

    const int* srcA = ei;
    const int* dstA = ei + NEDGES;

    char* p = (char*)d_ws;
    size_t off = 0;
    auto take = [&](size_t bytes) {
        char* r = p + off;
        off = (off + bytes + 255) & ~(size_t)255;
        return r;
    };
    int* rp   = (int*)take((NNODES + 1) * sizeof(int));
    int* cnt  = (int*)take(NNODES * sizeof(int));
    int* bsum = (int*)take(256 * sizeof(int));
    int* srcs = (int*)take(NEDGES * sizeof(int));
    u16* wT1  = (u16*)take(3 * 16384 * sizeof(u16));
    u16* wT2  = (u16*)take(3 * 16384 * sizeof(u16));
    u16* fwTc = (u16*)take(4 * 16384 * sizeof(u16));
    u16* xb   = (u16*)take((size_t)NNODES * D * sizeof(u16));
    u16* hb1  = (u16*)take((size_t)NNODES * D * sizeof(u16));
    u16* hb2  = (u16*)take((size_t)NNODES * D * sizeof(u16));
    u16* hb3  = (u16*)take((size_t)NNODES * D * sizeof(u16));
    (void)ws_size; (void)in_sizes; (void)n_in; (void)out_size;

    hipMemsetAsync(cnt, 0, NNODES * sizeof(int), stream);

    int nb = (NNODES + 255) / 256;
    k_hist<<<(NEDGES + 255) / 256, 256, 0, stream>>>(dstA, cnt);
    k_scan1<<<nb, 256, 0, stream>>>(cnt, rp, bsum);
    k_scan2<<<1, 256, 0, stream>>>(bsum, nb);
    k_add<<<nb, 256, 0, stream>>>(rp, bsum);
    k_scatter<<<(NEDGES + 255) / 256, 256, 0, stream>>>(srcA, dstA, rp, cnt, srcs);
    k_prep<<<(NNODES * 64 + 255) / 256, 256, 0, stream>>>(W1, W2, fw, x, wT1, wT2, fwTc, (u32*)xb);

    const u16* hin = xb;
    u16* houts[3] = {hb1, hb2, hb3};
    int gm = (NNODES + 127) / 128;  // 391
    for (int l = 0; l < 3; ++l) {
        k_mlp<<<gm, 256, 0, stream>>>((const uint4*)hin, rp, srcs, eps + l,
                                      wT1 + l * 16384, b1 + l * D,
                                      wT2 + l * 16384, b2 + l * D, houts[l]);
        hin = houts[l];
    }
    k_final<<<gm, 256, 0, stream>>>(xb, hb1, hb2, hb3, fwTc, fb, out);
}

// Round 5
// 298.693 us; speedup vs baseline: 1.1117x; 1.1117x over previous
//
#include <hip/hip_runtime.h>

#define NNODES 50000
#define NEDGES 640000
#define D 128

typedef unsigned short u16;
typedef unsigned int u32;
typedef __bf16 bf16x8 __attribute__((ext_vector_type(8)));
typedef float f32x4 __attribute__((ext_vector_type(4)));
union AB { uint4 u4; bf16x8 f; };

__device__ __forceinline__ u16 f2b(float f) {
    u32 u = __float_as_uint(f);
    return (u16)((u + 0x7fffu + ((u >> 16) & 1u)) >> 16);
}
__device__ __forceinline__ u32 pack2(float lo, float hi) {
    return (u32)f2b(lo) | ((u32)f2b(hi) << 16);
}
__device__ __forceinline__ float blo(u32 v) { return __uint_as_float(v << 16); }
__device__ __forceinline__ float bhi(u32 v) { return __uint_as_float(v & 0xffff0000u); }

__device__ __forceinline__ void acc8(float* a, uint4 v) {
    a[0] += blo(v.x); a[1] += bhi(v.x);
    a[2] += blo(v.y); a[3] += bhi(v.y);
    a[4] += blo(v.z); a[5] += bhi(v.z);
    a[6] += blo(v.w); a[7] += bhi(v.w);
}

// ---------------- CSR build ----------------

__global__ void k_hist(const int* __restrict__ dst, int* __restrict__ cnt) {
    int e = blockIdx.x * 256 + threadIdx.x;
    if (e < NEDGES) atomicAdd(&cnt[dst[e]], 1);
}

__global__ void k_scan1(const int* __restrict__ cnt, int* __restrict__ rp,
                        int* __restrict__ bsum) {
    __shared__ int s[256];
    int tid = threadIdx.x;
    int i = blockIdx.x * 256 + tid;
    int v = (i < NNODES) ? cnt[i] : 0;
    s[tid] = v;
    __syncthreads();
    for (int off = 1; off < 256; off <<= 1) {
        int t = (tid >= off) ? s[tid - off] : 0;
        __syncthreads();
        s[tid] += t;
        __syncthreads();
    }
    if (i < NNODES) rp[i] = s[tid] - v;
    if (tid == 255) bsum[blockIdx.x] = s[255];
}

__global__ void k_scan2(int* __restrict__ bsum, int nb) {
    __shared__ int s[256];
    int tid = threadIdx.x;
    int v = (tid < nb) ? bsum[tid] : 0;
    s[tid] = v;
    __syncthreads();
    for (int off = 1; off < 256; off <<= 1) {
        int t = (tid >= off) ? s[tid - off] : 0;
        __syncthreads();
        s[tid] += t;
        __syncthreads();
    }
    if (tid < nb) bsum[tid] = s[tid] - v;
}

__global__ void k_add(int* __restrict__ rp, const int* __restrict__ bsum) {
    int i = blockIdx.x * 256 + threadIdx.x;
    if (i < NNODES) rp[i] += bsum[blockIdx.x];
    if (i == 0) rp[NNODES] = NEDGES;
}

// reverse-fill using cnt itself (cnt is consumed; no separate fill array)
__global__ void k_scatter(const int* __restrict__ src, const int* __restrict__ dst,
                          const int* __restrict__ rp, int* __restrict__ cnt,
                          int* __restrict__ srcs) {
    int e = blockIdx.x * 256 + threadIdx.x;
    if (e < NEDGES) {
        int dn = dst[e];
        int old = atomicSub(&cnt[dn], 1);
        srcs[rp[dn] + old - 1] = src[e];
    }
}

// ---------------- weight prep (transpose->bf16) + x conversion, merged ----------------
__global__ void k_prep(const float* __restrict__ W1, const float* __restrict__ W2,
                       const float* __restrict__ fw, const float* __restrict__ x,
                       u16* __restrict__ wT1, u16* __restrict__ wT2,
                       u16* __restrict__ fwTc, u32* __restrict__ xb) {
    int idx = blockIdx.x * 256 + threadIdx.x;  // grid covers NNODES*64
    if (idx < 3 * 16384) {
        int l = idx >> 14, r = idx & 16383, n = r >> 7, k = r & 127;
        wT1[idx] = f2b(W1[l * 16384 + k * 128 + n]);
        wT2[idx] = f2b(W2[l * 16384 + k * 128 + n]);
    }
    if (idx < 4 * 16384) {
        int ch = idx >> 14, r = idx & 16383, n = r >> 7, k = r & 127;
        fwTc[idx] = f2b(fw[(ch * 128 + k) * 128 + n]);
    }
    if (idx < NNODES * 64) {
        float2 v = ((const float2*)x)[idx];
        xb[idx] = pack2(v.x, v.y);
    }
}

// ---------------- aggregation: standalone, high-occupancy, 8-deep gather ----------------
// 16 lanes/node, one node per group, grid = 50000*16/256 = 3125 (exact).
__global__ void k_agg(const uint4* __restrict__ h4, const int* __restrict__ rp,
                      const int* __restrict__ srcs, const float* __restrict__ epsp,
                      uint4* __restrict__ z4) {
    int tid = threadIdx.x;
    int c = tid & 15;                          // 16B chunk of the 256B row
    int node = (blockIdx.x * 256 + tid) >> 4;  // exact coverage
    int gbase = tid & 48;                      // group base lane within wave
    float sc = 1.0f + epsp[0];

    uint4 sv = h4[node * 16 + c];
    float acc[8];
    acc[0] = sc * blo(sv.x); acc[1] = sc * bhi(sv.x);
    acc[2] = sc * blo(sv.y); acc[3] = sc * bhi(sv.y);
    acc[4] = sc * blo(sv.z); acc[5] = sc * bhi(sv.z);
    acc[6] = sc * blo(sv.w); acc[7] = sc * bhi(sv.w);

    int beg = rp[node], end = rp[node + 1];
    for (int base = beg; base < end; base += 16) {
        int n = end - base; if (n > 16) n = 16;
        int myidx = (base + c < end) ? srcs[base + c] : 0;
        int j = 0;
        for (; j + 8 <= n; j += 8) {
            int s0 = __shfl(myidx, gbase + j + 0, 64);
            int s1 = __shfl(myidx, gbase + j + 1, 64);
            int s2 = __shfl(myidx, gbase + j + 2, 64);
            int s3 = __shfl(myidx, gbase + j + 3, 64);
            int s4 = __shfl(myidx, gbase + j + 4, 64);
            int s5 = __shfl(myidx, gbase + j + 5, 64);
            int s6 = __shfl(myidx, gbase + j + 6, 64);
            int s7 = __shfl(myidx, gbase + j + 7, 64);
            uint4 v0 = h4[s0 * 16 + c]; uint4 v1 = h4[s1 * 16 + c];
            uint4 v2 = h4[s2 * 16 + c]; uint4 v3 = h4[s3 * 16 + c];
            uint4 v4 = h4[s4 * 16 + c]; uint4 v5 = h4[s5 * 16 + c];
            uint4 v6 = h4[s6 * 16 + c]; uint4 v7 = h4[s7 * 16 + c];
            acc8(acc, v0); acc8(acc, v1); acc8(acc, v2); acc8(acc, v3);
            acc8(acc, v4); acc8(acc, v5); acc8(acc, v6); acc8(acc, v7);
        }
        for (; j + 4 <= n; j += 4) {
            int s0 = __shfl(myidx, gbase + j + 0, 64);
            int s1 = __shfl(myidx, gbase + j + 1, 64);
            int s2 = __shfl(myidx, gbase + j + 2, 64);
            int s3 = __shfl(myidx, gbase + j + 3, 64);
            uint4 v0 = h4[s0 * 16 + c]; uint4 v1 = h4[s1 * 16 + c];
            uint4 v2 = h4[s2 * 16 + c]; uint4 v3 = h4[s3 * 16 + c];
            acc8(acc, v0); acc8(acc, v1); acc8(acc, v2); acc8(acc, v3);
        }
        for (; j < n; ++j) {
            int s0 = __shfl(myidx, gbase + j, 64);
            uint4 v0 = h4[s0 * 16 + c];
            acc8(acc, v0);
        }
    }

    uint4 o;
    o.x = pack2(acc[0], acc[1]); o.y = pack2(acc[2], acc[3]);
    o.z = pack2(acc[4], acc[5]); o.w = pack2(acc[6], acc[7]);
    z4[node * 16 + c] = o;
}

// ---------------- MLP via MFMA, XOR-swizzled LDS ----------------
// 16B chunk ch of row r lives at slot (ch+r)&15 -> fragment reads become 2-way
// bank aliased (free) instead of 16-way (~5.7x).
__launch_bounds__(256, 2)
__global__ void k_mlp(const u16* __restrict__ A, const u16* __restrict__ wT1g,
                      const float* __restrict__ b1, const u16* __restrict__ wT2g,
                      const float* __restrict__ b2, u16* __restrict__ H) {
    __shared__ u16 Tb[128 * 128];    // 32 KB
    __shared__ u16 wbuf[128 * 128];  // 32 KB
    uint4* Tb4 = (uint4*)Tb;
    uint4* wb4 = (uint4*)wbuf;
    int tid = threadIdx.x;
    int r0 = blockIdx.x * 128;
    int wave = tid >> 6, lane = tid & 63, l16 = lane & 15, quad = lane >> 4;

    // stage W1^T (swizzled)
    {
        const uint4* g = (const uint4*)wT1g;
        for (int i = tid; i < 2048; i += 256) {
            int n = i >> 4, ch = i & 15;
            wb4[n * 16 + ((ch + n) & 15)] = g[i];
        }
    }

    // A-fragments straight from global (no cross-wave reuse)
    AB a[2][4];
#pragma unroll
    for (int s = 0; s < 2; ++s) {
        int row = r0 + wave * 32 + s * 16 + l16;
#pragma unroll
        for (int kb = 0; kb < 4; ++kb) {
            if (row < NNODES)
                a[s][kb].u4 = *(const uint4*)&A[row * 128 + kb * 32 + quad * 8];
            else
                a[s][kb].u4 = make_uint4(0, 0, 0, 0);
        }
    }
    __syncthreads();

    f32x4 acc[2][8];
#pragma unroll
    for (int col = 0; col < 8; ++col) {
        float bv = b1[col * 16 + l16];
        acc[0][col] = (f32x4){bv, bv, bv, bv};
        acc[1][col] = (f32x4){bv, bv, bv, bv};
    }
#pragma unroll
    for (int col = 0; col < 8; ++col) {
#pragma unroll
        for (int kb = 0; kb < 4; ++kb) {
            AB b;
            int n = col * 16 + l16;
            b.u4 = wb4[n * 16 + ((kb * 4 + quad + n) & 15)];
            acc[0][col] = __builtin_amdgcn_mfma_f32_16x16x32_bf16(a[0][kb].f, b.f, acc[0][col], 0, 0, 0);
            acc[1][col] = __builtin_amdgcn_mfma_f32_16x16x32_bf16(a[1][kb].f, b.f, acc[1][col], 0, 0, 0);
        }
    }

    // T = relu -> Tb (swizzled scalar u16 stores)
#pragma unroll
    for (int s = 0; s < 2; ++s)
#pragma unroll
        for (int col = 0; col < 8; ++col)
#pragma unroll
            for (int r = 0; r < 4; ++r) {
                int row = wave * 32 + s * 16 + quad * 4 + r;
                int kcol = col * 16 + l16;
                int ch = kcol >> 3;
                Tb[row * 128 + ((ch + row) & 15) * 8 + (kcol & 7)] =
                    f2b(fmaxf(acc[s][col][r], 0.f));
            }
    __syncthreads();

    // stage W2^T (swizzled, overwrite wbuf)
    {
        const uint4* g = (const uint4*)wT2g;
        for (int i = tid; i < 2048; i += 256) {
            int n = i >> 4, ch = i & 15;
            wb4[n * 16 + ((ch + n) & 15)] = g[i];
        }
    }
    AB a2[2][4];
#pragma unroll
    for (int s = 0; s < 2; ++s) {
        int m = wave * 32 + s * 16 + l16;
#pragma unroll
        for (int kb = 0; kb < 4; ++kb)
            a2[s][kb].u4 = Tb4[m * 16 + ((kb * 4 + quad + m) & 15)];
    }
    __syncthreads();

#pragma unroll
    for (int col = 0; col < 8; ++col) {
        float bv = b2[col * 16 + l16];
        acc[0][col] = (f32x4){bv, bv, bv, bv};
        acc[1][col] = (f32x4){bv, bv, bv, bv};
    }
#pragma unroll
    for (int col = 0; col < 8; ++col) {
#pragma unroll
        for (int kb = 0; kb < 4; ++kb) {
            AB b;
            int n = col * 16 + l16;
            b.u4 = wb4[n * 16 + ((kb * 4 + quad + n) & 15)];
            acc[0][col] = __builtin_amdgcn_mfma_f32_16x16x32_bf16(a2[0][kb].f, b.f, acc[0][col], 0, 0, 0);
            acc[1][col] = __builtin_amdgcn_mfma_f32_16x16x32_bf16(a2[1][kb].f, b.f, acc[1][col], 0, 0, 0);
        }
    }
    __syncthreads();  // a2 reads of Tb done before overwrite

#pragma unroll
    for (int s = 0; s < 2; ++s)
#pragma unroll
        for (int col = 0; col < 8; ++col)
#pragma unroll
            for (int r = 0; r < 4; ++r) {
                int row = wave * 32 + s * 16 + quad * 4 + r;
                int kcol = col * 16 + l16;
                int ch = kcol >> 3;
                Tb[row * 128 + ((ch + row) & 15) * 8 + (kcol & 7)] =
                    f2b(fmaxf(acc[s][col][r], 0.f));
            }
    __syncthreads();

    // coalesced copy Tb -> H (de-swizzle)
    for (int i = tid; i < 2048; i += 256) {
        int r = i >> 4, ch = i & 15;
        int grow = r0 + r;
        if (grow < NNODES)
            *(uint4*)&H[grow * 128 + ch * 8] = Tb4[r * 16 + ((ch + r) & 15)];
    }
}

// ---------------- final: out = concat(x,h1,h2,h3) @ fw + fb, fp32 out ----------------
__launch_bounds__(256, 2)
__global__ void k_final(const u16* __restrict__ xb, const u16* __restrict__ h1,
                        const u16* __restrict__ h2b, const u16* __restrict__ h3,
                        const u16* __restrict__ fwTc, const float* __restrict__ fb,
                        float* __restrict__ out) {
    __shared__ u16 wbuf[128 * 128];
    uint4* wb4 = (uint4*)wbuf;
    int tid = threadIdx.x;
    int wave = tid >> 6, lane = tid & 63, l16 = lane & 15, quad = lane >> 4;
    int r0 = blockIdx.x * 128 + wave * 32;

    f32x4 acc[2][8];
#pragma unroll
    for (int col = 0; col < 8; ++col) {
        float bv = fb[col * 16 + l16];
        acc[0][col] = (f32x4){bv, bv, bv, bv};
        acc[1][col] = (f32x4){bv, bv, bv, bv};
    }

    const u16* chin[4] = {xb, h1, h2b, h3};
    for (int chn = 0; chn < 4; ++chn) {
        __syncthreads();
        {
            const uint4* g = (const uint4*)(fwTc + chn * 16384);
            for (int i = tid; i < 2048; i += 256) {
                int n = i >> 4, ch = i & 15;
                wb4[n * 16 + ((ch + n) & 15)] = g[i];
            }
        }
        const u16* cp = chin[chn];
        AB a[2][4];
#pragma unroll
        for (int s = 0; s < 2; ++s) {
            int row = r0 + s * 16 + l16;
#pragma unroll
            for (int kb = 0; kb < 4; ++kb) {
                if (row < NNODES)
                    a[s][kb].u4 = *(const uint4*)&cp[row * 128 + kb * 32 + quad * 8];
                else
                    a[s][kb].u4 = make_uint4(0, 0, 0, 0);
            }
        }
        __syncthreads();
#pragma unroll
        for (int col = 0; col < 8; ++col) {
#pragma unroll
            for (int kb = 0; kb < 4; ++kb) {
                AB b;
                int n = col * 16 + l16;
                b.u4 = wb4[n * 16 + ((kb * 4 + quad + n) & 15)];
                acc[0][col] = __builtin_amdgcn_mfma_f32_16x16x32_bf16(a[0][kb].f, b.f, acc[0][col], 0, 0, 0);
                acc[1][col] = __builtin_amdgcn_mfma_f32_16x16x32_bf16(a[1][kb].f, b.f, acc[1][col], 0, 0, 0);
            }
        }
    }

#pragma unroll
    for (int s = 0; s < 2; ++s)
#pragma unroll
        for (int col = 0; col < 8; ++col)
#pragma unroll
            for (int r = 0; r < 4; ++r) {
                int row = r0 + s * 16 + quad * 4 + r;
                if (row < NNODES) out[row * 128 + col * 16 + l16] = acc[s][col][r];
            }
}

extern "C" void kernel_launch(void* const* d_in, const int* in_sizes, int n_in,
                              void* d_out, int out_size, void* d_ws, size_t ws_size,
                              hipStream_t stream) {
    const float* x   = (const float*)d_in[0];
    const int*   ei  = (const int*)d_in[1];
    const float* W1  = (const float*)d_in[2];
    const float* b1  = (const float*)d_in[3];
    const float* W2  = (const float*)d_in[4];
    const float* b2  = (const float*)d_in[5];
    const float* eps = (const float*)d_in[6];
    const float* fw  = (const float*)d_in[7];
    const float* fb  = (const float*)d_in[8];
    float* out = (float*)d_out;

    const int* srcA = ei;
    const int* dstA = ei + NEDGES;

    char* p = (char*)d_ws;
    size_t off = 0;
    auto take = [&](size_t bytes) {
        char* r = p + off;
        off = (off + bytes + 255) & ~(size_t)255;
        return r;
    };
    int* rp   = (int*)take((NNODES + 1) * sizeof(int));
    int* cnt  = (int*)take(NNODES * sizeof(int));
    int* bsum = (int*)take(256 * sizeof(int));
    int* srcs = (int*)take(NEDGES * sizeof(int));
    u16* wT1  = (u16*)take(3 * 16384 * sizeof(u16));
    u16* wT2  = (u16*)take(3 * 16384 * sizeof(u16));
    u16* fwTc = (u16*)take(4 * 16384 * sizeof(u16));
    u16* xb   = (u16*)take((size_t)NNODES * D * sizeof(u16));
    u16* zb   = (u16*)take((size_t)NNODES * D * sizeof(u16));
    u16* hb1  = (u16*)take((size_t)NNODES * D * sizeof(u16));
    u16* hb2  = (u16*)take((size_t)NNODES * D * sizeof(u16));
    u16* hb3  = (u16*)take((size_t)NNODES * D * sizeof(u16));
    (void)ws_size; (void)in_sizes; (void)n_in; (void)out_size;

    hipMemsetAsync(cnt, 0, NNODES * sizeof(int), stream);

    int nb = (NNODES + 255) / 256;
    k_hist<<<(NEDGES + 255) / 256, 256, 0, stream>>>(dstA, cnt);
    k_scan1<<<nb, 256, 0, stream>>>(cnt, rp, bsum);
    k_scan2<<<1, 256, 0, stream>>>(bsum, nb);
    k_add<<<nb, 256, 0, stream>>>(rp, bsum);
    k_scatter<<<(NEDGES + 255) / 256, 256, 0, stream>>>(srcA, dstA, rp, cnt, srcs);
    k_prep<<<(NNODES * 64 + 255) / 256, 256, 0, stream>>>(W1, W2, fw, x, wT1, wT2, fwTc, (u32*)xb);

    const u16* hin = xb;
    u16* houts[3] = {hb1, hb2, hb3};
    int gm = (NNODES + 127) / 128;  // 391
    for (int l = 0; l < 3; ++l) {
        k_agg<<<NNODES * 16 / 256, 256, 0, stream>>>((const uint4*)hin, rp, srcs, eps + l, (uint4*)zb);
        k_mlp<<<gm, 256, 0, stream>>>(zb, wT1 + l * 16384, b1 + l * D,
                                      wT2 + l * 16384, b2 + l * D, houts[l]);
        hin = houts[l];
    }
    k_final<<<gm, 256, 0, stream>>>(xb, hb1, hb2, hb3, fwTc, fb, out);
}